// Round 9
// baseline (835.483 us; speedup 1.0000x reference)
//
#include <hip/hip_runtime.h>

#define N_USERS  100000
#define EMBED    128
#define NBINS    64        // degree clamp for sort bins (Poisson(16) max ~45)

typedef __attribute__((ext_vector_type(8))) short bf16x8;
typedef __attribute__((ext_vector_type(4))) float f32x4;
typedef __attribute__((ext_vector_type(4))) uint  u32x4;

// ---------------------------------------------------------------- row pointers
__global__ __launch_bounds__(256) void rowptr_kernel(const int* __restrict__ rows,
                                                     int* __restrict__ row_ptr,
                                                     int n_rows, int n_edges) {
  int r = blockIdx.x * blockDim.x + threadIdx.x;
  if (r > n_rows) return;
  int lo = 0, hi = n_edges;
  while (lo < hi) {
    int mid = (lo + hi) >> 1;
    if (rows[mid] < r) lo = mid + 1; else hi = mid;
  }
  row_ptr[r] = lo;
}

// ---------------------------------------------------------------- degree sort
__global__ __launch_bounds__(64) void histzero_kernel(int* __restrict__ hist) {
  hist[threadIdx.x] = 0;
}

__global__ __launch_bounds__(256) void deghist_kernel(const int* __restrict__ row_ptr,
                                                      int* __restrict__ hist) {
  int r = blockIdx.x * blockDim.x + threadIdx.x;
  if (r >= N_USERS) return;
  int deg = row_ptr[r + 1] - row_ptr[r];
  atomicAdd(hist + min(deg, NBINS - 1), 1);
}

// Exclusive offsets for DESCENDING degree order (heavy rows first -> LPT).
__global__ __launch_bounds__(64) void degscan_kernel(const int* __restrict__ hist,
                                                     int* __restrict__ binoff) {
  int lane = threadIdx.x;
  int d = NBINS - 1 - lane;          // lane 0 <-> highest degree bin
  int c = hist[d];
  int x = c;
  #pragma unroll
  for (int s = 1; s < 64; s <<= 1) {
    int y = __shfl_up(x, s);
    if (lane >= s) x += y;
  }
  binoff[d] = x - c;                 // exclusive prefix in descending order
}

__global__ __launch_bounds__(256) void degscatter_kernel(const int* __restrict__ row_ptr,
                                                         int* __restrict__ binoff,
                                                         int* __restrict__ rowperm) {
  int r = blockIdx.x * blockDim.x + threadIdx.x;
  if (r >= N_USERS) return;
  int deg = row_ptr[r + 1] - row_ptr[r];
  int pos = atomicAdd(binoff + min(deg, NBINS - 1), 1);
  rowperm[pos] = r;
}

// ---------------------------------------------------------------- W -> Wt bf16
__global__ __launch_bounds__(256) void wconv_kernel(const float* __restrict__ W0,
                                                    const float* __restrict__ W1,
                                                    uint* __restrict__ Wt0,
                                                    uint* __restrict__ Wt1) {
  const float* W  = blockIdx.x ? W1 : W0;
  uint*        Wt = blockIdx.x ? Wt1 : Wt0;
  for (int idx = threadIdx.x; idx < 128 * 64; idx += 256) {
    int n = idx >> 6;
    int kp = idx & 63;
    float a = W[(2 * kp) * 128 + n];
    float b = W[(2 * kp + 1) * 128 + n];
    uint o;
    asm("v_cvt_pk_bf16_f32 %0, %1, %2" : "=v"(o) : "v"(a), "v"(b));
    Wt[n * 64 + kp] = o;
  }
}

// ---------------------------------------------------------------- MFMA GEMM (R4 shape)
__global__ __launch_bounds__(256) void gemm_kernel(const float* __restrict__ X,
                                                   const ushort* __restrict__ Wt,
                                                   ushort* __restrict__ Y,
                                                   float* __restrict__ Xcopy) {
  const int tid  = threadIdx.x;
  const int wave = tid >> 6;
  const int lane = tid & 63;
  const int l15  = lane & 15;
  const int lg   = lane >> 4;
  const int m    = blockIdx.x * 64 + wave * 16 + l15;
  const int mc   = m < N_USERS ? m : N_USERS - 1;
  const bool act = m < N_USERS;
  const float* xrow = X + (size_t)mc * EMBED;

  f32x4 acc[8];
  #pragma unroll
  for (int t = 0; t < 8; ++t) acc[t] = (f32x4){0.f, 0.f, 0.f, 0.f};

  #pragma unroll
  for (int s = 0; s < 4; ++s) {
    const int k0 = s * 32 + lg * 8;
    float4 xa = *(const float4*)(xrow + k0);
    float4 xb = *(const float4*)(xrow + k0 + 4);
    if (Xcopy && act) {
      *(float4*)(Xcopy + (size_t)m * EMBED + k0)     = xa;
      *(float4*)(Xcopy + (size_t)m * EMBED + k0 + 4) = xb;
    }
    union { bf16x8 v; uint u[4]; } bfr;
    asm("v_cvt_pk_bf16_f32 %0, %1, %2" : "=v"(bfr.u[0]) : "v"(xa.x), "v"(xa.y));
    asm("v_cvt_pk_bf16_f32 %0, %1, %2" : "=v"(bfr.u[1]) : "v"(xa.z), "v"(xa.w));
    asm("v_cvt_pk_bf16_f32 %0, %1, %2" : "=v"(bfr.u[2]) : "v"(xb.x), "v"(xb.y));
    asm("v_cvt_pk_bf16_f32 %0, %1, %2" : "=v"(bfr.u[3]) : "v"(xb.z), "v"(xb.w));
    #pragma unroll
    for (int nt = 0; nt < 8; ++nt) {
      union { bf16x8 v; uint4 u; } afr;
      afr.u = *(const uint4*)(Wt + (size_t)(nt * 16 + l15) * 128 + k0);
      acc[nt] = __builtin_amdgcn_mfma_f32_16x16x32_bf16(afr.v, bfr.v, acc[nt], 0, 0, 0);
    }
  }

  if (act) {
    ushort* yrow = Y + (size_t)m * EMBED;
    #pragma unroll
    for (int nt = 0; nt < 8; ++nt) {
      uint2 o;
      asm("v_cvt_pk_bf16_f32 %0, %1, %2" : "=v"(o.x) : "v"(acc[nt][0]), "v"(acc[nt][1]));
      asm("v_cvt_pk_bf16_f32 %0, %1, %2" : "=v"(o.y) : "v"(acc[nt][2]), "v"(acc[nt][3]));
      *(uint2*)(yrow + nt * 16 + lg * 4) = o;
    }
  }
}

// ---------------------------------------------------------------- SpMM + residual
// R4 structure; dst rows assigned via degree-sorted rowperm so the 4 rows in
// each wave have ~equal degree (removes max-degree lockstep waste; traffic
// is unchanged -> clean divergence-vs-service-rate discriminator).
__device__ __forceinline__ void fma8(float* acc, u32x4 g, float v) {
  acc[0] = fmaf(v, __uint_as_float(g[0] << 16),         acc[0]);
  acc[1] = fmaf(v, __uint_as_float(g[0] & 0xffff0000u), acc[1]);
  acc[2] = fmaf(v, __uint_as_float(g[1] << 16),         acc[2]);
  acc[3] = fmaf(v, __uint_as_float(g[1] & 0xffff0000u), acc[3]);
  acc[4] = fmaf(v, __uint_as_float(g[2] << 16),         acc[4]);
  acc[5] = fmaf(v, __uint_as_float(g[2] & 0xffff0000u), acc[5]);
  acc[6] = fmaf(v, __uint_as_float(g[3] << 16),         acc[6]);
  acc[7] = fmaf(v, __uint_as_float(g[3] & 0xffff0000u), acc[7]);
}

__global__ __launch_bounds__(256) void spmm_kernel(const ushort* __restrict__ XT,
                                                   const float* __restrict__ X,
                                                   const int* __restrict__ row_ptr,
                                                   const int* __restrict__ rowperm,
                                                   const int* __restrict__ cols,
                                                   const float* __restrict__ vals,
                                                   float* __restrict__ OUT) {
  const int tid = threadIdx.x;
  const int l   = tid & 15;        // 8 cols / 16B per lane
  const int rg  = tid >> 4;        // 16 rows per block
  const int idx = blockIdx.x * 16 + rg;
  if (idx >= N_USERS) return;
  const int row = rowperm[idx];
  const int start = row_ptr[row];
  const int end   = row_ptr[row + 1];
  const u32x4* XT4 = (const u32x4*)XT;   // row stride = 16

  float acc[8];
  {
    float4 r0 = *(const float4*)(X + (size_t)row * EMBED + l * 8);
    float4 r1 = *(const float4*)(X + (size_t)row * EMBED + l * 8 + 4);
    acc[0] = r0.x; acc[1] = r0.y; acc[2] = r0.z; acc[3] = r0.w;
    acc[4] = r1.x; acc[5] = r1.y; acc[6] = r1.z; acc[7] = r1.w;
  }

  int e = start;
  int e_pre = (start + 3) & ~3;    // peel to int4 alignment
  if (e_pre > end) e_pre = end;
  for (; e < e_pre; ++e) {
    u32x4 g = XT4[(size_t)cols[e] * 16 + l];
    fma8(acc, g, vals[e]);
  }
  for (; e + 4 <= end; e += 4) {
    int4   ca = *(const int4*)(cols + e);
    float4 va = *(const float4*)(vals + e);
    u32x4 g0 = XT4[(size_t)ca.x * 16 + l];
    u32x4 g1 = XT4[(size_t)ca.y * 16 + l];
    u32x4 g2 = XT4[(size_t)ca.z * 16 + l];
    u32x4 g3 = XT4[(size_t)ca.w * 16 + l];
    fma8(acc, g0, va.x); fma8(acc, g1, va.y);
    fma8(acc, g2, va.z); fma8(acc, g3, va.w);
  }
  for (; e < end; ++e) {
    u32x4 g = XT4[(size_t)cols[e] * 16 + l];
    fma8(acc, g, vals[e]);
  }

  float4 o0 = {acc[0], acc[1], acc[2], acc[3]};
  float4 o1 = {acc[4], acc[5], acc[6], acc[7]};
  *(float4*)(OUT + (size_t)row * EMBED + l * 8)     = o0;
  *(float4*)(OUT + (size_t)row * EMBED + l * 8 + 4) = o1;
}

// ---------------------------------------------------------------- launch
extern "C" void kernel_launch(void* const* d_in, const int* in_sizes, int n_in,
                              void* d_out, int out_size, void* d_ws, size_t ws_size,
                              hipStream_t stream) {
  const float* user_embeds = (const float*)d_in[0];
  const int*   s_rows      = (const int*)d_in[1];
  const int*   s_cols      = (const int*)d_in[2];
  const float* s_values    = (const float*)d_in[3];
  const float* W0          = (const float*)d_in[4];
  const float* W1          = (const float*)d_in[5];
  float* out = (float*)d_out;

  const int n_edges = in_sizes[1];
  const size_t layer = (size_t)N_USERS * EMBED;

  char* ws = (char*)d_ws;
  ushort* xt      = (ushort*)ws;  ws += layer * sizeof(ushort);          // 25.6 MB
  ushort* Wt0     = (ushort*)ws;  ws += 128 * 128 * sizeof(ushort);
  ushort* Wt1     = (ushort*)ws;  ws += 128 * 128 * sizeof(ushort);
  int*    row_ptr = (int*)ws;     ws += (N_USERS + 1) * sizeof(int) + 12;
  int*    rowperm = (int*)ws;     ws += (size_t)N_USERS * sizeof(int);
  int*    hist    = (int*)ws;     ws += NBINS * sizeof(int);
  int*    binoff  = (int*)ws;

  rowptr_kernel<<<(N_USERS + 1 + 255) / 256, 256, 0, stream>>>(
      s_rows, row_ptr, N_USERS, n_edges);
  wconv_kernel<<<2, 256, 0, stream>>>(W0, W1, (uint*)Wt0, (uint*)Wt1);
  histzero_kernel<<<1, NBINS, 0, stream>>>(hist);
  deghist_kernel<<<(N_USERS + 255) / 256, 256, 0, stream>>>(row_ptr, hist);
  degscan_kernel<<<1, NBINS, 0, stream>>>(hist, binoff);
  degscatter_kernel<<<(N_USERS + 255) / 256, 256, 0, stream>>>(
      row_ptr, binoff, rowperm);

  const ushort* Wtl[2] = {Wt0, Wt1};
  for (int l = 0; l < 2; ++l) {
    // Layer 0 reads the ORIGINAL input (d_out is zeroed by the harness);
    // gemm0 streams user_embeds -> out[0].
    const float* Xl = (l == 0) ? user_embeds : (out + l * layer);
    gemm_kernel<<<(N_USERS + 63) / 64, 256, 0, stream>>>(
        Xl, Wtl[l], xt, l == 0 ? out : nullptr);
    spmm_kernel<<<(N_USERS + 15) / 16, 256, 0, stream>>>(
        xt, Xl, row_ptr, rowperm, s_cols, s_values, out + (l + 1) * layer);
  }
}

// Round 10
// 262.516 us; speedup vs baseline: 3.1826x; 3.1826x over previous
//
#include <hip/hip_runtime.h>

#define N_USERS  100000
#define EMBED    128
#define NBINS    64
#define HBLK     ((N_USERS + 255) / 256)   // 391 histogram blocks

typedef __attribute__((ext_vector_type(8))) short bf16x8;
typedef __attribute__((ext_vector_type(4))) float f32x4;
typedef __attribute__((ext_vector_type(4))) uint  u32x4;

// ---------------------------------------------------------------- row pointers
__global__ __launch_bounds__(256) void rowptr_kernel(const int* __restrict__ rows,
                                                     int* __restrict__ row_ptr,
                                                     int n_rows, int n_edges) {
  int r = blockIdx.x * blockDim.x + threadIdx.x;
  if (r > n_rows) return;
  int lo = 0, hi = n_edges;
  while (lo < hi) {
    int mid = (lo + hi) >> 1;
    if (rows[mid] < r) lo = mid + 1; else hi = mid;
  }
  row_ptr[r] = lo;
}

// ---------------------------------------------------------------- degree sort
__global__ __launch_bounds__(64) void histzero_kernel(int* __restrict__ ghist) {
  ghist[threadIdx.x] = 0;
}

// Per-block LDS histogram; one global atomic per (block,bin); the returned
// old value is this block's stable base within the bin.
__global__ __launch_bounds__(256) void deghist_kernel(const int* __restrict__ row_ptr,
                                                      int* __restrict__ ghist,
                                                      int* __restrict__ blockbase) {
  __shared__ int lh[NBINS];
  const int t = threadIdx.x;
  if (t < NBINS) lh[t] = 0;
  __syncthreads();
  const int r = blockIdx.x * 256 + t;
  if (r < N_USERS) {
    int deg = min(row_ptr[r + 1] - row_ptr[r], NBINS - 1);
    atomicAdd(&lh[deg], 1);
  }
  __syncthreads();
  if (t < NBINS) {
    int base = atomicAdd(&ghist[t], lh[t]);
    blockbase[blockIdx.x * NBINS + t] = base;
  }
}

// Exclusive offsets for DESCENDING degree order (heavy rows first -> LPT).
__global__ __launch_bounds__(64) void degscan_kernel(const int* __restrict__ ghist,
                                                     int* __restrict__ binoff) {
  int lane = threadIdx.x;
  int d = NBINS - 1 - lane;            // lane 0 <-> highest-degree bin
  int c = ghist[d];
  int x = c;
  #pragma unroll
  for (int s = 1; s < 64; s <<= 1) {
    int y = __shfl_up(x, s);
    if (lane >= s) x += y;
  }
  binoff[d] = x - c;
}

__global__ __launch_bounds__(256) void degscatter_kernel(const int* __restrict__ row_ptr,
                                                         const int* __restrict__ binoff,
                                                         const int* __restrict__ blockbase,
                                                         int* __restrict__ rowperm) {
  __shared__ int lh[NBINS];
  const int t = threadIdx.x;
  if (t < NBINS) lh[t] = 0;
  __syncthreads();
  const int r = blockIdx.x * 256 + t;
  if (r < N_USERS) {
    int bin   = min(row_ptr[r + 1] - row_ptr[r], NBINS - 1);
    int lrank = atomicAdd(&lh[bin], 1);
    int pos   = binoff[bin] + blockbase[blockIdx.x * NBINS + bin] + lrank;
    rowperm[pos] = r;
  }
}

// ---------------------------------------------------------------- W -> Wt bf16
__global__ __launch_bounds__(256) void wconv_kernel(const float* __restrict__ W0,
                                                    const float* __restrict__ W1,
                                                    uint* __restrict__ Wt0,
                                                    uint* __restrict__ Wt1) {
  const float* W  = blockIdx.x ? W1 : W0;
  uint*        Wt = blockIdx.x ? Wt1 : Wt0;
  for (int idx = threadIdx.x; idx < 128 * 64; idx += 256) {
    int n = idx >> 6;
    int kp = idx & 63;
    float a = W[(2 * kp) * 128 + n];
    float b = W[(2 * kp + 1) * 128 + n];
    uint o;
    asm("v_cvt_pk_bf16_f32 %0, %1, %2" : "=v"(o) : "v"(a), "v"(b));
    Wt[n * 64 + kp] = o;
  }
}

// ---------------------------------------------------------------- MFMA GEMM (R4 shape)
__global__ __launch_bounds__(256) void gemm_kernel(const float* __restrict__ X,
                                                   const ushort* __restrict__ Wt,
                                                   ushort* __restrict__ Y,
                                                   float* __restrict__ Xcopy) {
  const int tid  = threadIdx.x;
  const int wave = tid >> 6;
  const int lane = tid & 63;
  const int l15  = lane & 15;
  const int lg   = lane >> 4;
  const int m    = blockIdx.x * 64 + wave * 16 + l15;
  const int mc   = m < N_USERS ? m : N_USERS - 1;
  const bool act = m < N_USERS;
  const float* xrow = X + (size_t)mc * EMBED;

  f32x4 acc[8];
  #pragma unroll
  for (int t = 0; t < 8; ++t) acc[t] = (f32x4){0.f, 0.f, 0.f, 0.f};

  #pragma unroll
  for (int s = 0; s < 4; ++s) {
    const int k0 = s * 32 + lg * 8;
    float4 xa = *(const float4*)(xrow + k0);
    float4 xb = *(const float4*)(xrow + k0 + 4);
    if (Xcopy && act) {
      *(float4*)(Xcopy + (size_t)m * EMBED + k0)     = xa;
      *(float4*)(Xcopy + (size_t)m * EMBED + k0 + 4) = xb;
    }
    union { bf16x8 v; uint u[4]; } bfr;
    asm("v_cvt_pk_bf16_f32 %0, %1, %2" : "=v"(bfr.u[0]) : "v"(xa.x), "v"(xa.y));
    asm("v_cvt_pk_bf16_f32 %0, %1, %2" : "=v"(bfr.u[1]) : "v"(xa.z), "v"(xa.w));
    asm("v_cvt_pk_bf16_f32 %0, %1, %2" : "=v"(bfr.u[2]) : "v"(xb.x), "v"(xb.y));
    asm("v_cvt_pk_bf16_f32 %0, %1, %2" : "=v"(bfr.u[3]) : "v"(xb.z), "v"(xb.w));
    #pragma unroll
    for (int nt = 0; nt < 8; ++nt) {
      union { bf16x8 v; uint4 u; } afr;
      afr.u = *(const uint4*)(Wt + (size_t)(nt * 16 + l15) * 128 + k0);
      acc[nt] = __builtin_amdgcn_mfma_f32_16x16x32_bf16(afr.v, bfr.v, acc[nt], 0, 0, 0);
    }
  }

  if (act) {
    ushort* yrow = Y + (size_t)m * EMBED;
    #pragma unroll
    for (int nt = 0; nt < 8; ++nt) {
      uint2 o;
      asm("v_cvt_pk_bf16_f32 %0, %1, %2" : "=v"(o.x) : "v"(acc[nt][0]), "v"(acc[nt][1]));
      asm("v_cvt_pk_bf16_f32 %0, %1, %2" : "=v"(o.y) : "v"(acc[nt][2]), "v"(acc[nt][3]));
      *(uint2*)(yrow + nt * 16 + lg * 4) = o;
    }
  }
}

// ---------------------------------------------------------------- SpMM + residual
// R4 structure; dst rows assigned via degree-sorted rowperm (LPT) so the 16
// rows in a block (4 per wave) have ~equal degree. Gather traffic unchanged.
__device__ __forceinline__ void fma8(float* acc, u32x4 g, float v) {
  acc[0] = fmaf(v, __uint_as_float(g[0] << 16),         acc[0]);
  acc[1] = fmaf(v, __uint_as_float(g[0] & 0xffff0000u), acc[1]);
  acc[2] = fmaf(v, __uint_as_float(g[1] << 16),         acc[2]);
  acc[3] = fmaf(v, __uint_as_float(g[1] & 0xffff0000u), acc[3]);
  acc[4] = fmaf(v, __uint_as_float(g[2] << 16),         acc[4]);
  acc[5] = fmaf(v, __uint_as_float(g[2] & 0xffff0000u), acc[5]);
  acc[6] = fmaf(v, __uint_as_float(g[3] << 16),         acc[6]);
  acc[7] = fmaf(v, __uint_as_float(g[3] & 0xffff0000u), acc[7]);
}

__global__ __launch_bounds__(256) void spmm_kernel(const ushort* __restrict__ XT,
                                                   const float* __restrict__ X,
                                                   const int* __restrict__ row_ptr,
                                                   const int* __restrict__ rowperm,
                                                   const int* __restrict__ cols,
                                                   const float* __restrict__ vals,
                                                   float* __restrict__ OUT) {
  const int tid = threadIdx.x;
  const int l   = tid & 15;
  const int rg  = tid >> 4;
  const int idx = blockIdx.x * 16 + rg;
  if (idx >= N_USERS) return;
  const int row = rowperm[idx];
  const int start = row_ptr[row];
  const int end   = row_ptr[row + 1];
  const u32x4* XT4 = (const u32x4*)XT;

  float acc[8];
  {
    float4 r0 = *(const float4*)(X + (size_t)row * EMBED + l * 8);
    float4 r1 = *(const float4*)(X + (size_t)row * EMBED + l * 8 + 4);
    acc[0] = r0.x; acc[1] = r0.y; acc[2] = r0.z; acc[3] = r0.w;
    acc[4] = r1.x; acc[5] = r1.y; acc[6] = r1.z; acc[7] = r1.w;
  }

  int e = start;
  int e_pre = (start + 3) & ~3;
  if (e_pre > end) e_pre = end;
  for (; e < e_pre; ++e) {
    u32x4 g = XT4[(size_t)cols[e] * 16 + l];
    fma8(acc, g, vals[e]);
  }
  for (; e + 4 <= end; e += 4) {
    int4   ca = *(const int4*)(cols + e);
    float4 va = *(const float4*)(vals + e);
    u32x4 g0 = XT4[(size_t)ca.x * 16 + l];
    u32x4 g1 = XT4[(size_t)ca.y * 16 + l];
    u32x4 g2 = XT4[(size_t)ca.z * 16 + l];
    u32x4 g3 = XT4[(size_t)ca.w * 16 + l];
    fma8(acc, g0, va.x); fma8(acc, g1, va.y);
    fma8(acc, g2, va.z); fma8(acc, g3, va.w);
  }
  for (; e < end; ++e) {
    u32x4 g = XT4[(size_t)cols[e] * 16 + l];
    fma8(acc, g, vals[e]);
  }

  float4 o0 = {acc[0], acc[1], acc[2], acc[3]};
  float4 o1 = {acc[4], acc[5], acc[6], acc[7]};
  *(float4*)(OUT + (size_t)row * EMBED + l * 8)     = o0;
  *(float4*)(OUT + (size_t)row * EMBED + l * 8 + 4) = o1;
}

// ---------------------------------------------------------------- launch
extern "C" void kernel_launch(void* const* d_in, const int* in_sizes, int n_in,
                              void* d_out, int out_size, void* d_ws, size_t ws_size,
                              hipStream_t stream) {
  const float* user_embeds = (const float*)d_in[0];
  const int*   s_rows      = (const int*)d_in[1];
  const int*   s_cols      = (const int*)d_in[2];
  const float* s_values    = (const float*)d_in[3];
  const float* W0          = (const float*)d_in[4];
  const float* W1          = (const float*)d_in[5];
  float* out = (float*)d_out;

  const int n_edges = in_sizes[1];
  const size_t layer = (size_t)N_USERS * EMBED;

  char* ws = (char*)d_ws;
  ushort* xt        = (ushort*)ws;  ws += layer * sizeof(ushort);          // 25.6 MB
  ushort* Wt0       = (ushort*)ws;  ws += 128 * 128 * sizeof(ushort);
  ushort* Wt1       = (ushort*)ws;  ws += 128 * 128 * sizeof(ushort);
  int*    row_ptr   = (int*)ws;     ws += (N_USERS + 1) * sizeof(int) + 12;
  int*    rowperm   = (int*)ws;     ws += (size_t)N_USERS * sizeof(int);
  int*    ghist     = (int*)ws;     ws += NBINS * sizeof(int);
  int*    binoff    = (int*)ws;     ws += NBINS * sizeof(int);
  int*    blockbase = (int*)ws;                                            // 391*64 ints

  rowptr_kernel<<<(N_USERS + 1 + 255) / 256, 256, 0, stream>>>(
      s_rows, row_ptr, N_USERS, n_edges);
  wconv_kernel<<<2, 256, 0, stream>>>(W0, W1, (uint*)Wt0, (uint*)Wt1);
  histzero_kernel<<<1, NBINS, 0, stream>>>(ghist);
  deghist_kernel<<<HBLK, 256, 0, stream>>>(row_ptr, ghist, blockbase);
  degscan_kernel<<<1, NBINS, 0, stream>>>(ghist, binoff);
  degscatter_kernel<<<HBLK, 256, 0, stream>>>(row_ptr, binoff, blockbase, rowperm);

  const ushort* Wtl[2] = {Wt0, Wt1};
  for (int l = 0; l < 2; ++l) {
    // Layer 0 reads the ORIGINAL input (d_out is zeroed by the harness);
    // gemm0 streams user_embeds -> out[0].
    const float* Xl = (l == 0) ? user_embeds : (out + l * layer);
    gemm_kernel<<<(N_USERS + 63) / 64, 256, 0, stream>>>(
        Xl, Wtl[l], xt, l == 0 ? out : nullptr);
    spmm_kernel<<<(N_USERS + 15) / 16, 256, 0, stream>>>(
        xt, Xl, row_ptr, rowperm, s_cols, s_values, out + (l + 1) * layer);
  }
}

// Round 11
// 201.140 us; speedup vs baseline: 4.1537x; 1.3051x over previous
//
#include <hip/hip_runtime.h>

#define N_USERS  100000
#define EMBED    128

typedef __attribute__((ext_vector_type(8))) short bf16x8;
typedef __attribute__((ext_vector_type(4))) float f32x4;

// ---------------------------------------------------------------- row pointers
__global__ __launch_bounds__(256) void rowptr_kernel(const int* __restrict__ rows,
                                                     int* __restrict__ row_ptr,
                                                     int n_rows, int n_edges) {
  int r = blockIdx.x * blockDim.x + threadIdx.x;
  if (r > n_rows) return;
  int lo = 0, hi = n_edges;
  while (lo < hi) {
    int mid = (lo + hi) >> 1;
    if (rows[mid] < r) lo = mid + 1; else hi = mid;
  }
  row_ptr[r] = lo;
}

// ---------------------------------------------------------------- W -> Wt bf16
// Wt[n][k] = bf16(W[k][n]); 64 uint per row (bf16 pairs along k).
__global__ __launch_bounds__(256) void wconv_kernel(const float* __restrict__ W0,
                                                    const float* __restrict__ W1,
                                                    uint* __restrict__ Wt0,
                                                    uint* __restrict__ Wt1) {
  const float* W  = blockIdx.x ? W1 : W0;
  uint*        Wt = blockIdx.x ? Wt1 : Wt0;
  for (int idx = threadIdx.x; idx < 128 * 64; idx += 256) {
    int n = idx >> 6;
    int kp = idx & 63;
    float a = W[(2 * kp) * 128 + n];
    float b = W[(2 * kp + 1) * 128 + n];
    uint o;
    asm("v_cvt_pk_bf16_f32 %0, %1, %2" : "=v"(o) : "v"(a), "v"(b));
    Wt[n * 64 + kp] = o;
  }
}

// ---------------------------------------------------------------- MFMA GEMM
// Y8(int8)[m][n] = quant(X @ W) with per-row scale; scale[m] = rowmax/127.
// R4 MFMA structure; epilogue does in-register row-absmax + int8 pack.
// Optionally streams X -> Xcopy (layer-0 materialization of out[0]).
__global__ __launch_bounds__(256) void gemm_kernel(const float* __restrict__ X,
                                                   const ushort* __restrict__ Wt,
                                                   unsigned char* __restrict__ Y8,
                                                   float* __restrict__ scale_arr,
                                                   float* __restrict__ Xcopy) {
  const int tid  = threadIdx.x;
  const int wave = tid >> 6;
  const int lane = tid & 63;
  const int l15  = lane & 15;
  const int lg   = lane >> 4;
  const int m    = blockIdx.x * 64 + wave * 16 + l15;
  const int mc   = m < N_USERS ? m : N_USERS - 1;
  const bool act = m < N_USERS;
  const float* xrow = X + (size_t)mc * EMBED;

  f32x4 acc[8];
  #pragma unroll
  for (int t = 0; t < 8; ++t) acc[t] = (f32x4){0.f, 0.f, 0.f, 0.f};

  #pragma unroll
  for (int s = 0; s < 4; ++s) {
    const int k0 = s * 32 + lg * 8;
    float4 xa = *(const float4*)(xrow + k0);
    float4 xb = *(const float4*)(xrow + k0 + 4);
    if (Xcopy && act) {
      *(float4*)(Xcopy + (size_t)m * EMBED + k0)     = xa;
      *(float4*)(Xcopy + (size_t)m * EMBED + k0 + 4) = xb;
    }
    union { bf16x8 v; uint u[4]; } bfr;
    asm("v_cvt_pk_bf16_f32 %0, %1, %2" : "=v"(bfr.u[0]) : "v"(xa.x), "v"(xa.y));
    asm("v_cvt_pk_bf16_f32 %0, %1, %2" : "=v"(bfr.u[1]) : "v"(xa.z), "v"(xa.w));
    asm("v_cvt_pk_bf16_f32 %0, %1, %2" : "=v"(bfr.u[2]) : "v"(xb.x), "v"(xb.y));
    asm("v_cvt_pk_bf16_f32 %0, %1, %2" : "=v"(bfr.u[3]) : "v"(xb.z), "v"(xb.w));
    #pragma unroll
    for (int nt = 0; nt < 8; ++nt) {
      union { bf16x8 v; uint4 u; } afr;
      afr.u = *(const uint4*)(Wt + (size_t)(nt * 16 + l15) * 128 + k0);
      acc[nt] = __builtin_amdgcn_mfma_f32_16x16x32_bf16(afr.v, bfr.v, acc[nt], 0, 0, 0);
    }
  }

  if (act) {
    // row absmax: this lane has 32 of the row's 128 elems; lanes sharing l15
    // (lane ^16, ^32) hold the rest.
    float amax = 0.f;
    #pragma unroll
    for (int nt = 0; nt < 8; ++nt)
      #pragma unroll
      for (int i = 0; i < 4; ++i) amax = fmaxf(amax, fabsf(acc[nt][i]));
    amax = fmaxf(amax, __shfl_xor(amax, 16));
    amax = fmaxf(amax, __shfl_xor(amax, 32));
    const float inv = amax > 0.f ? 127.0f / amax : 0.f;
    if (lg == 0) scale_arr[m] = amax * (1.0f / 127.0f);

    unsigned char* yrow = Y8 + (size_t)m * EMBED;
    #pragma unroll
    for (int nt = 0; nt < 8; ++nt) {
      uint q = 0;
      #pragma unroll
      for (int i = 0; i < 4; ++i) {
        int qi = __float2int_rn(acc[nt][i] * inv) + 128;   // 1..255
        q |= (uint)qi << (8 * i);
      }
      *(uint*)(yrow + nt * 16 + lg * 4) = q;
    }
  }
}

// ---------------------------------------------------------------- SpMM + residual
// OUT[r] = X[r] + sum_e vals[e] * dequant(XT8[cols[e]])
//        = (sum_e vs_e * q) - 128 * (sum_e vs_e) + X[r],  vs_e = vals[e]*scale[c]
// 8 lanes per row (16 cols / 16B gather each -> int8 row = 2x64B lines),
// 32 rows per 256-thread block.
__device__ __forceinline__ void fma16(float* acc, uint4 g, float vs) {
  float f;
  #define CVT_ACC(word, b, slot)                                        \
    asm("v_cvt_f32_ubyte" #b " %0, %1" : "=v"(f) : "v"(word));          \
    acc[slot] = fmaf(vs, f, acc[slot]);
  CVT_ACC(g.x, 0, 0)  CVT_ACC(g.x, 1, 1)  CVT_ACC(g.x, 2, 2)  CVT_ACC(g.x, 3, 3)
  CVT_ACC(g.y, 0, 4)  CVT_ACC(g.y, 1, 5)  CVT_ACC(g.y, 2, 6)  CVT_ACC(g.y, 3, 7)
  CVT_ACC(g.z, 0, 8)  CVT_ACC(g.z, 1, 9)  CVT_ACC(g.z, 2, 10) CVT_ACC(g.z, 3, 11)
  CVT_ACC(g.w, 0, 12) CVT_ACC(g.w, 1, 13) CVT_ACC(g.w, 2, 14) CVT_ACC(g.w, 3, 15)
  #undef CVT_ACC
}

__global__ __launch_bounds__(256) void spmm_kernel(const unsigned char* __restrict__ XT8,
                                                   const float* __restrict__ scale_arr,
                                                   const float* __restrict__ X,
                                                   const int* __restrict__ row_ptr,
                                                   const int* __restrict__ cols,
                                                   const float* __restrict__ vals,
                                                   float* __restrict__ OUT) {
  const int tid = threadIdx.x;
  const int l   = tid & 7;         // 16 cols / 16B per lane
  const int rg  = tid >> 3;        // 32 rows per block
  const int row = blockIdx.x * 32 + rg;
  if (row >= N_USERS) return;
  const int start = row_ptr[row];
  const int end   = row_ptr[row + 1];
  const uint4* XT4 = (const uint4*)XT8;   // row stride = 8 uint4

  float acc[16];
  #pragma unroll
  for (int j = 0; j < 16; ++j) acc[j] = 0.f;
  float vsum = 0.f;

  int e = start;
  int e_pre = (start + 3) & ~3;    // peel to int4 alignment
  if (e_pre > end) e_pre = end;
  for (; e < e_pre; ++e) {
    int c = cols[e];
    float vs = vals[e] * scale_arr[c];
    vsum += vs;
    fma16(acc, XT4[(size_t)c * 8 + l], vs);
  }
  for (; e + 4 <= end; e += 4) {
    int4   ca = *(const int4*)(cols + e);
    float4 va = *(const float4*)(vals + e);
    float s0 = scale_arr[ca.x], s1 = scale_arr[ca.y];
    float s2 = scale_arr[ca.z], s3 = scale_arr[ca.w];
    uint4 g0 = XT4[(size_t)ca.x * 8 + l];
    uint4 g1 = XT4[(size_t)ca.y * 8 + l];
    uint4 g2 = XT4[(size_t)ca.z * 8 + l];
    uint4 g3 = XT4[(size_t)ca.w * 8 + l];
    float vs0 = va.x * s0, vs1 = va.y * s1, vs2 = va.z * s2, vs3 = va.w * s3;
    vsum += vs0 + vs1 + vs2 + vs3;
    fma16(acc, g0, vs0);
    fma16(acc, g1, vs1);
    fma16(acc, g2, vs2);
    fma16(acc, g3, vs3);
  }
  for (; e < end; ++e) {
    int c = cols[e];
    float vs = vals[e] * scale_arr[c];
    vsum += vs;
    fma16(acc, XT4[(size_t)c * 8 + l], vs);
  }

  const float corr = vsum * 128.0f;
  const float* xr = X + (size_t)row * EMBED + l * 16;
  float*       orow = OUT + (size_t)row * EMBED + l * 16;
  #pragma unroll
  for (int k = 0; k < 4; ++k) {
    float4 r = *(const float4*)(xr + k * 4);
    float4 o = {acc[k * 4 + 0] - corr + r.x,
                acc[k * 4 + 1] - corr + r.y,
                acc[k * 4 + 2] - corr + r.z,
                acc[k * 4 + 3] - corr + r.w};
    *(float4*)(orow + k * 4) = o;
  }
}

// ---------------------------------------------------------------- launch
extern "C" void kernel_launch(void* const* d_in, const int* in_sizes, int n_in,
                              void* d_out, int out_size, void* d_ws, size_t ws_size,
                              hipStream_t stream) {
  const float* user_embeds = (const float*)d_in[0];
  const int*   s_rows      = (const int*)d_in[1];
  const int*   s_cols      = (const int*)d_in[2];
  const float* s_values    = (const float*)d_in[3];
  const float* W0          = (const float*)d_in[4];
  const float* W1          = (const float*)d_in[5];
  float* out = (float*)d_out;

  const int n_edges = in_sizes[1];
  const size_t layer = (size_t)N_USERS * EMBED;

  char* ws = (char*)d_ws;
  unsigned char* xt8 = (unsigned char*)ws;  ws += layer;                     // 12.8 MB
  float*  scale_arr  = (float*)ws;          ws += N_USERS * sizeof(float);   // 400 KB
  ushort* Wt0        = (ushort*)ws;         ws += 128 * 128 * sizeof(ushort);
  ushort* Wt1        = (ushort*)ws;         ws += 128 * 128 * sizeof(ushort);
  int*    row_ptr    = (int*)ws;

  rowptr_kernel<<<(N_USERS + 1 + 255) / 256, 256, 0, stream>>>(
      s_rows, row_ptr, N_USERS, n_edges);
  wconv_kernel<<<2, 256, 0, stream>>>(W0, W1, (uint*)Wt0, (uint*)Wt1);

  const ushort* Wtl[2] = {Wt0, Wt1};
  for (int l = 0; l < 2; ++l) {
    // Layer 0 reads the ORIGINAL input (d_out is zeroed by the harness);
    // gemm0 streams user_embeds -> out[0].
    const float* Xl = (l == 0) ? user_embeds : (out + l * layer);
    gemm_kernel<<<(N_USERS + 63) / 64, 256, 0, stream>>>(
        Xl, Wtl[l], xt8, scale_arr, l == 0 ? out : nullptr);
    spmm_kernel<<<(N_USERS + 31) / 32, 256, 0, stream>>>(
        xt8, scale_arr, Xl, row_ptr, s_cols, s_values, out + (l + 1) * layer);
  }
}